// Round 6
// baseline (712.753 us; speedup 1.0000x reference)
//
#include <hip/hip_runtime.h>
#include <math.h>

#define B 16
#define N 4096
#define NPTS (B * N)   // 65536
#define NBK 2048       // knn grid blocks
#define NBT 1024       // tail grid blocks
#define EPSF 1e-6f
#define S8(i) ((i) * 8)  // 64B-padded double slot

__device__ __forceinline__ float waveReduceSum(float v) {
#pragma unroll
    for (int m = 32; m > 0; m >>= 1) v += __shfl_xor(v, m, 64);
    return v;
}

__device__ __forceinline__ void leaky3(float px, float py, float pz,
                                       float dx, float dy, float dz, float s,
                                       float& ox, float& oy, float& oz) {
    float dotr = px * dx + py * dy + pz * dz;
    float dsq = dx * dx + dy * dy + dz * dz;
    float dot = s * dotr;
    float coef = (dot >= 0.f) ? 0.f : (dot / (dsq + EPSF));
    ox = s * px - coef * dx;
    oy = s * py - coef * dy;
    oz = s * pz - coef * dz;
}

__device__ __forceinline__ void mk_muisd(const double* st, int cnt, double M,
                                         float* smu, float* sisd) {
    const int i = threadIdx.x;
    if (i < cnt) {
        double m = st[S8(i)] / M;
        double v = st[S8(cnt + i)] / M - m * m;
        smu[i] = (float)m;
        sisd[i] = (float)(1.0 / sqrt(v + 1e-5));
    }
}

// fence + counter: returns true for exactly one (the last-finishing) block.
__device__ __forceinline__ bool lastBlockDone(unsigned* cnt, unsigned nblk) {
    __shared__ unsigned lb;
    __threadfence();
    __syncthreads();
    if (threadIdx.x == 0) lb = (atomicAdd(cnt, 1u) == nblk - 1u) ? 1u : 0u;
    __syncthreads();
    return lb != 0u;
}

// Sum nv values over nblk per-block f32 partials (value-major) in f64 -> st[S8(v)].
__device__ __forceinline__ void finalize(const float* part, int nv, int nblk,
                                         double* st, double* redd) {
    const int v = threadIdx.x >> 2, sub = threadIdx.x & 3;
    double s = 0.0;
    if (v < nv) {
        const float* p = part + (size_t)v * nblk + sub * (nblk >> 2);
        for (int i = 0; i < (nblk >> 2); ++i) s += (double)p[i];
    }
    redd[threadIdx.x] = s;
    __syncthreads();
    if (threadIdx.x < nv) {
        const int b4 = threadIdx.x << 2;
        st[S8(threadIdx.x)] = redd[b4] + redd[b4 + 1] + redd[b4 + 2] + redd[b4 + 3];
    }
}

struct Feat {
    float cx, cy, cz, e0x, e0y, e0z, e2x, e2y, e2z;
};

__device__ __forceinline__ Feat make_feat(const float* __restrict__ pc,
                                          const int* __restrict__ nbr, int pid) {
    const int b = pid >> 12, n = pid & (N - 1);
    const float* base = pc + (size_t)b * (3 * N);
    Feat f;
    f.cx = base[3 * n];
    f.cy = base[3 * n + 1];
    f.cz = base[3 * n + 2];
    const int jn = nbr[pid];
    float nx = base[3 * jn], ny = base[3 * jn + 1], nz = base[3 * jn + 2];
    f.e0x = nx - f.cx;
    f.e0y = ny - f.cy;
    f.e0z = nz - f.cz;
    f.e2x = ny * f.cz - nz * f.cy;
    f.e2y = nz * f.cx - nx * f.cz;
    f.e2z = nx * f.cy - ny * f.cx;
    return f;
}

// ---------------- K1: nearest-other + layer0 BN stats -------------------------------
// f32 proxy scan (self-chunk peeled -> 6 VALU/pair), butterfly top-2 merge,
// f64 rescore; then st0 partials + last-block finalize.
#define QW 8
__global__ __launch_bounds__(256) void k_knn(const float* __restrict__ pc,
                                             const float* __restrict__ Wf0,
                                             int* __restrict__ nbrbest,
                                             float* __restrict__ part,
                                             unsigned* __restrict__ cnt,
                                             double* __restrict__ st0) {
    __shared__ float sx[N], sy[N], sz[N];
    __shared__ float ws0[63], sred[168];
    __shared__ double redd[256];
    const int b = blockIdx.x >> 7;
    const int qblk = (blockIdx.x & 127) * 32;
    const float* base = pc + (size_t)b * (N * 3);
    for (int j = threadIdx.x; j < N; j += 256) {
        sx[j] = base[3 * j + 0];
        sy[j] = base[3 * j + 1];
        sz[j] = base[3 * j + 2];
    }
    if (threadIdx.x < 63) ws0[threadIdx.x] = Wf0[threadIdx.x];
    __syncthreads();
    const int wid = threadIdx.x >> 6, lane = threadIdx.x & 63;
    const int q0 = qblk + wid * QW;
    float qx[QW], qy[QW], qz[QW], bv[QW];
    int bi[QW], bq[QW];
#pragma unroll
    for (int q = 0; q < QW; ++q) {
        qx[q] = sx[q0 + q];
        qy[q] = sy[q0 + q];
        qz[q] = sz[q0 + q];
        bv[q] = -3.0e38f;
        bi[q] = 0;
    }
    const int scq = q0 >> 6;  // all 8 queries share this self-chunk
#pragma unroll 4
    for (int ch = 0; ch < N / 64; ++ch) {
        if (ch == scq) continue;
        const int j = ch * 64 + lane;
        const float xd = sx[j], yd = sy[j], zd = sz[j];
        const float nr2h = -0.5f * (xd * xd + yd * yd + zd * zd);
#pragma unroll
        for (int q = 0; q < QW; ++q) {
            float pd = fmaf(qx[q], xd, fmaf(qy[q], yd, fmaf(qz[q], zd, nr2h)));
            bool upd = pd > bv[q];
            bv[q] = upd ? pd : bv[q];
            bi[q] = upd ? j : bi[q];
        }
    }
    {  // peeled self chunk (with exclusion test)
        const int j = scq * 64 + lane;
        const float xd = sx[j], yd = sy[j], zd = sz[j];
        const float nr2h = -0.5f * (xd * xd + yd * yd + zd * zd);
#pragma unroll
        for (int q = 0; q < QW; ++q) {
            float pd = fmaf(qx[q], xd, fmaf(qy[q], yd, fmaf(qz[q], zd, nr2h)));
            bool upd = (pd > bv[q]) && (j != q0 + q);
            bv[q] = upd ? pd : bv[q];
            bi[q] = upd ? j : bi[q];
        }
    }
#pragma unroll
    for (int q = 0; q < QW; ++q) {
        float a0v = bv[q], a1v = -3.0e38f;
        int a0i = bi[q], a1i = 0x7fffffff;
#pragma unroll
        for (int m = 1; m < 64; m <<= 1) {
            float b0v = __shfl_xor(a0v, m, 64), b1v = __shfl_xor(a1v, m, 64);
            int b0i = __shfl_xor(a0i, m, 64), b1i = __shfl_xor(a1i, m, 64);
            bool bf = (b0v > a0v) || (b0v == a0v && b0i < a0i);
            float c0v = bf ? a0v : b0v;
            int c0i = bf ? a0i : b0i;
            float c1v = bf ? b1v : a1v;
            int c1i = bf ? b1i : a1i;
            a0v = bf ? b0v : a0v;
            a0i = bf ? b0i : a0i;
            bool cf = (c0v > c1v) || (c0v == c1v && c0i < c1i);
            a1v = cf ? c0v : c1v;
            a1i = cf ? c0i : c1i;
        }
        const int i0 = a0i, i1 = a1i;
        double dxa = (double)qx[q] - (double)sx[i0];
        double dya = (double)qy[q] - (double)sy[i0];
        double dza = (double)qz[q] - (double)sz[i0];
        double d0 = dxa * dxa + dya * dya + dza * dza;
        double dxb = (double)qx[q] - (double)sx[i1];
        double dyb = (double)qy[q] - (double)sy[i1];
        double dzb = (double)qz[q] - (double)sz[i1];
        double d1 = dxb * dxb + dyb * dyb + dzb * dzb;
        bool take1 = (d1 < d0) || (d1 == d0 && i1 < i0);
        int best = take1 ? i1 : i0;
        bq[q] = best;
        if (lane == 0) nbrbest[(size_t)b * N + q0 + q] = best;
    }
    // ---- st0 partials: lane < 21 owns channel=lane for this wave's 8 queries ----
    float s1 = 0.f, s2 = 0.f;
    if (lane < 21) {
        const float w0 = ws0[3 * lane], w1 = ws0[3 * lane + 1], w2 = ws0[3 * lane + 2];
#pragma unroll
        for (int q = 0; q < QW; ++q) {
            const int sq = q0 + q, jn = bq[q];
            const float cx = sx[sq], cy = sy[sq], cz = sz[sq];
            const float nx = sx[jn], ny = sy[jn], nz = sz[jn];
            const float e0x = nx - cx, e0y = ny - cy, e0z = nz - cz;
            const float e2x = ny * cz - nz * cy;
            const float e2y = nz * cx - nx * cz;
            const float e2z = nx * cy - ny * cx;
            float pSx = w1 * cx, pSy = w1 * cy, pSz = w1 * cz;
            float nS = sqrtf(pSx * pSx + pSy * pSy + pSz * pSz) + EPSF;
            float px = w0 * e0x + w1 * cx + w2 * e2x;
            float py = w0 * e0y + w1 * cy + w2 * e2y;
            float pz = w0 * e0z + w1 * cz + w2 * e2z;
            float nN = sqrtf(px * px + py * py + pz * pz) + EPSF;
            s1 += nS + nN;
            s2 += nS * nS + nN * nN;
        }
        sred[wid * 42 + lane] = s1;
        sred[wid * 42 + 21 + lane] = s2;
    }
    __syncthreads();
    if (threadIdx.x < 42) {
        float p = sred[threadIdx.x] + sred[42 + threadIdx.x] +
                  sred[84 + threadIdx.x] + sred[126 + threadIdx.x];
        part[(size_t)threadIdx.x * NBK + blockIdx.x] = p;
    }
    if (lastBlockDone(cnt, NBK)) finalize(part, 42, NBK, st0, redd);
}

// ---------------- K2: layer0 apply -> xbuf + LDS, layer1 BN stats -------------------
__global__ __launch_bounds__(256) void k_l0st1(
    const float* __restrict__ pc, const int* __restrict__ nbr,
    const float* __restrict__ Wf0, const float* __restrict__ Wd0,
    const float* __restrict__ g0, const float* __restrict__ b0,
    const float* __restrict__ Wf1, const double* __restrict__ st0,
    float* __restrict__ xbuf, float* __restrict__ part,
    unsigned* __restrict__ cnt, double* __restrict__ st1) {
    __shared__ float wf0[63], wd0[63], wf1[441], gg[21], bbs[21], mu[21], isd[21];
    __shared__ float xs[63 * 64];
    __shared__ double redd[256];
    if (threadIdx.x < 63) {
        wf0[threadIdx.x] = Wf0[threadIdx.x];
        wd0[threadIdx.x] = Wd0[threadIdx.x];
    }
    for (int i = threadIdx.x; i < 441; i += 256) wf1[i] = Wf1[i];
    if (threadIdx.x < 21) {
        gg[threadIdx.x] = g0[threadIdx.x];
        bbs[threadIdx.x] = b0[threadIdx.x];
    }
    mk_muisd(st0, 21, (double)NPTS * 2.0, mu, isd);
    __syncthreads();
    const int lane = threadIdx.x & 63, grp = threadIdx.x >> 6;
    const int pid = blockIdx.x * 64 + lane;
    Feat f = make_feat(pc, nbr, pid);
    const int cbase = grp * 6;
#pragma unroll
    for (int k = 0; k < 6; ++k) {
        const int c = cbase + k;
        if (c >= 21) break;
        float w0 = wf0[3 * c], w1 = wf0[3 * c + 1], w2 = wf0[3 * c + 2];
        float u0 = wd0[3 * c], u1 = wd0[3 * c + 1], u2 = wd0[3 * c + 2];
        float pSx = w1 * f.cx, pSy = w1 * f.cy, pSz = w1 * f.cz;
        float nS = sqrtf(pSx * pSx + pSy * pSy + pSz * pSz) + EPSF;
        float sS = ((nS - mu[c]) * isd[c] * gg[c] + bbs[c]) / nS;
        float oSx, oSy, oSz;
        leaky3(pSx, pSy, pSz, u1 * f.cx, u1 * f.cy, u1 * f.cz, sS, oSx, oSy, oSz);
        float px = w0 * f.e0x + w1 * f.cx + w2 * f.e2x;
        float py = w0 * f.e0y + w1 * f.cy + w2 * f.e2y;
        float pz = w0 * f.e0z + w1 * f.cz + w2 * f.e2z;
        float dx = u0 * f.e0x + u1 * f.cx + u2 * f.e2x;
        float dy = u0 * f.e0y + u1 * f.cy + u2 * f.e2y;
        float dz = u0 * f.e0z + u1 * f.cz + u2 * f.e2z;
        float nN = sqrtf(px * px + py * py + pz * pz) + EPSF;
        float sN = ((nN - mu[c]) * isd[c] * gg[c] + bbs[c]) / nN;
        float oNx, oNy, oNz;
        leaky3(px, py, pz, dx, dy, dz, sN, oNx, oNy, oNz);
        float x0 = 0.5f * (oSx + oNx), x1 = 0.5f * (oSy + oNy), x2 = 0.5f * (oSz + oNz);
        xs[(3 * c + 0) * 64 + lane] = x0;
        xs[(3 * c + 1) * 64 + lane] = x1;
        xs[(3 * c + 2) * 64 + lane] = x2;
        xbuf[(size_t)(3 * c + 0) * NPTS + pid] = x0;
        xbuf[(size_t)(3 * c + 1) * NPTS + pid] = x1;
        xbuf[(size_t)(3 * c + 2) * NPTS + pid] = x2;
    }
    __syncthreads();
    float xl[63];
#pragma unroll
    for (int ff = 0; ff < 63; ++ff) xl[ff] = xs[ff * 64 + lane];
#pragma unroll
    for (int k = 0; k < 6; ++k) {
        const int c = cbase + k;
        if (c >= 21) break;
        float p0 = 0.f, p1 = 0.f, p2 = 0.f;
#pragma unroll
        for (int j = 0; j < 21; ++j) {
            float w = wf1[c * 21 + j];
            p0 = fmaf(w, xl[3 * j + 0], p0);
            p1 = fmaf(w, xl[3 * j + 1], p1);
            p2 = fmaf(w, xl[3 * j + 2], p2);
        }
        float nn = sqrtf(p0 * p0 + p1 * p1 + p2 * p2) + EPSF;
        float r1 = waveReduceSum(nn);
        float r2 = waveReduceSum(nn * nn);
        if (lane == 0) {
            part[(size_t)c * NBT + blockIdx.x] = r1;
            part[(size_t)(21 + c) * NBT + blockIdx.x] = r2;
        }
    }
    if (lastBlockDone(cnt, NBT)) finalize(part, 42, NBT, st1, redd);
}

// ---------------- K3: layer1 apply (in-place) + bn1 stats ---------------------------
__global__ __launch_bounds__(256) void k_l1stB(
    float* __restrict__ xbuf, const float* __restrict__ Wf1,
    const float* __restrict__ Wd1, const float* __restrict__ g1,
    const float* __restrict__ b1, const double* __restrict__ st1,
    float* __restrict__ part, unsigned* __restrict__ cnt,
    double* __restrict__ stB) {
    __shared__ float wf1[441], wd1[441], gg[21], bbs[21], mu[21], isd[21];
    __shared__ double redd[256];
    for (int i = threadIdx.x; i < 441; i += 256) {
        wf1[i] = Wf1[i];
        wd1[i] = Wd1[i];
    }
    if (threadIdx.x < 21) {
        gg[threadIdx.x] = g1[threadIdx.x];
        bbs[threadIdx.x] = b1[threadIdx.x];
    }
    mk_muisd(st1, 21, (double)NPTS, mu, isd);
    __syncthreads();
    const int lane = threadIdx.x & 63, grp = threadIdx.x >> 6;
    const int pid = blockIdx.x * 64 + lane;
    float xl[63];
#pragma unroll
    for (int ff = 0; ff < 63; ++ff) xl[ff] = xbuf[(size_t)ff * NPTS + pid];
    __syncthreads();  // all reads before any in-place write (pid columns are block-local)
    const int cbase = grp * 6;
#pragma unroll
    for (int k = 0; k < 6; ++k) {
        const int c = cbase + k;
        if (c >= 21) break;
        float p0 = 0.f, p1 = 0.f, p2 = 0.f, d0 = 0.f, d1 = 0.f, d2 = 0.f;
#pragma unroll
        for (int j = 0; j < 21; ++j) {
            float w = wf1[c * 21 + j], u = wd1[c * 21 + j];
            p0 = fmaf(w, xl[3 * j + 0], p0);
            p1 = fmaf(w, xl[3 * j + 1], p1);
            p2 = fmaf(w, xl[3 * j + 2], p2);
            d0 = fmaf(u, xl[3 * j + 0], d0);
            d1 = fmaf(u, xl[3 * j + 1], d1);
            d2 = fmaf(u, xl[3 * j + 2], d2);
        }
        float nn = sqrtf(p0 * p0 + p1 * p1 + p2 * p2) + EPSF;
        float s = ((nn - mu[c]) * isd[c] * gg[c] + bbs[c]) / nn;
        float ox, oy, oz;
        leaky3(p0, p1, p2, d0, d1, d2, s, ox, oy, oz);
        xbuf[(size_t)(3 * c + 0) * NPTS + pid] = ox;
        xbuf[(size_t)(3 * c + 1) * NPTS + pid] = oy;
        xbuf[(size_t)(3 * c + 2) * NPTS + pid] = oz;
        float on = sqrtf(ox * ox + oy * oy + oz * oz) + EPSF;
        float r1 = waveReduceSum(on);
        float r2 = waveReduceSum(on * on);
        if (lane == 0) {
            part[(size_t)c * NBT + blockIdx.x] = r1;
            part[(size_t)(21 + c) * NBT + blockIdx.x] = r2;
        }
    }
    if (lastBlockDone(cnt, NBT)) finalize(part, 42, NBT, stB, redd);
}

// ---------------- K4: bn1 apply (in-place) + layer2 BN stats ------------------------
__global__ __launch_bounds__(256) void k_bn1st2(
    float* __restrict__ xbuf, const float* __restrict__ gbn,
    const float* __restrict__ bbn, const float* __restrict__ Wf2,
    const double* __restrict__ stB, float* __restrict__ part,
    unsigned* __restrict__ cnt, double* __restrict__ st2) {
    __shared__ float wf2[63], gg[21], bbs[21], mu[21], isd[21];
    __shared__ float zs[63 * 64];
    __shared__ double redd[256];
    if (threadIdx.x < 63) wf2[threadIdx.x] = Wf2[threadIdx.x];
    if (threadIdx.x < 21) {
        gg[threadIdx.x] = gbn[threadIdx.x];
        bbs[threadIdx.x] = bbn[threadIdx.x];
    }
    mk_muisd(stB, 21, (double)NPTS, mu, isd);
    __syncthreads();
    const int lane = threadIdx.x & 63, grp = threadIdx.x >> 6;
    const int pid = blockIdx.x * 64 + lane;
    const int cbase = grp * 6;
#pragma unroll
    for (int k = 0; k < 6; ++k) {
        const int c = cbase + k;
        if (c >= 21) break;
        float y0 = xbuf[(size_t)(3 * c + 0) * NPTS + pid];
        float y1 = xbuf[(size_t)(3 * c + 1) * NPTS + pid];
        float y2 = xbuf[(size_t)(3 * c + 2) * NPTS + pid];
        float nn = sqrtf(y0 * y0 + y1 * y1 + y2 * y2) + EPSF;
        float sc = ((nn - mu[c]) * isd[c] * gg[c] + bbs[c]) / nn;
        y0 *= sc; y1 *= sc; y2 *= sc;
        zs[(3 * c + 0) * 64 + lane] = y0;
        zs[(3 * c + 1) * 64 + lane] = y1;
        zs[(3 * c + 2) * 64 + lane] = y2;
        xbuf[(size_t)(3 * c + 0) * NPTS + pid] = y0;
        xbuf[(size_t)(3 * c + 1) * NPTS + pid] = y1;
        xbuf[(size_t)(3 * c + 2) * NPTS + pid] = y2;
    }
    __syncthreads();
    if (grp < 3) {
        float p0 = 0.f, p1 = 0.f, p2 = 0.f;
#pragma unroll
        for (int j = 0; j < 21; ++j) {
            float w = wf2[grp * 21 + j];
            p0 = fmaf(w, zs[(3 * j + 0) * 64 + lane], p0);
            p1 = fmaf(w, zs[(3 * j + 1) * 64 + lane], p1);
            p2 = fmaf(w, zs[(3 * j + 2) * 64 + lane], p2);
        }
        float nn = sqrtf(p0 * p0 + p1 * p1 + p2 * p2) + EPSF;
        float r1 = waveReduceSum(nn);
        float r2 = waveReduceSum(nn * nn);
        if (lane == 0) {
            part[(size_t)grp * NBT + blockIdx.x] = r1;
            part[(size_t)(3 + grp) * NBT + blockIdx.x] = r2;
        }
    }
    if (lastBlockDone(cnt, NBT)) finalize(part, 6, NBT, st2, redd);
}

// ---------------- K5: layer2 apply + per-batch reduce + output ----------------------
__global__ __launch_bounds__(256) void k_accfin(
    const float* __restrict__ xbuf, const float* __restrict__ Wf2,
    const float* __restrict__ Wd2, const float* __restrict__ g2,
    const float* __restrict__ b2, const double* __restrict__ st2,
    double* __restrict__ acc, unsigned* __restrict__ cnt,
    float* __restrict__ out) {
    __shared__ float wf2[63], wd2[63], gg[3], bbs[3], mu[3], isd[3];
    if (threadIdx.x < 63) {
        wf2[threadIdx.x] = Wf2[threadIdx.x];
        wd2[threadIdx.x] = Wd2[threadIdx.x];
    }
    if (threadIdx.x < 3) {
        gg[threadIdx.x] = g2[threadIdx.x];
        bbs[threadIdx.x] = b2[threadIdx.x];
    }
    mk_muisd(st2, 3, (double)NPTS, mu, isd);
    __syncthreads();
    const int lane = threadIdx.x & 63, grp = threadIdx.x >> 6;
    const int pid = blockIdx.x * 64 + lane;
    const int b = pid >> 12;
    if (grp < 3) {
        float p0 = 0.f, p1 = 0.f, p2 = 0.f, d0 = 0.f, d1 = 0.f, d2 = 0.f;
#pragma unroll
        for (int j = 0; j < 21; ++j) {
            float x0 = xbuf[(size_t)(3 * j + 0) * NPTS + pid];
            float x1 = xbuf[(size_t)(3 * j + 1) * NPTS + pid];
            float x2 = xbuf[(size_t)(3 * j + 2) * NPTS + pid];
            float w = wf2[grp * 21 + j], u = wd2[grp * 21 + j];
            p0 = fmaf(w, x0, p0);
            p1 = fmaf(w, x1, p1);
            p2 = fmaf(w, x2, p2);
            d0 = fmaf(u, x0, d0);
            d1 = fmaf(u, x1, d1);
            d2 = fmaf(u, x2, d2);
        }
        float nn = sqrtf(p0 * p0 + p1 * p1 + p2 * p2) + EPSF;
        float s = ((nn - mu[grp]) * isd[grp] * gg[grp] + bbs[grp]) / nn;
        float ox, oy, oz;
        leaky3(p0, p1, p2, d0, d1, d2, s, ox, oy, oz);
        float rx = waveReduceSum(ox);
        float ry = waveReduceSum(oy);
        float rz = waveReduceSum(oz);
        if (lane == 0) {
            atomicAdd(&acc[S8(b * 9 + grp * 3 + 0)], (double)rx);
            atomicAdd(&acc[S8(b * 9 + grp * 3 + 1)], (double)ry);
            atomicAdd(&acc[S8(b * 9 + grp * 3 + 2)], (double)rz);
        }
    }
    if (lastBlockDone(cnt, NBT)) {
        if (threadIdx.x < B * 9)
            out[threadIdx.x] = (float)(acc[S8(threadIdx.x)] * (1.0 / (double)N));
    }
}

extern "C" void kernel_launch(void* const* d_in, const int* in_sizes, int n_in,
                              void* d_out, int out_size, void* d_ws, size_t ws_size,
                              hipStream_t stream) {
    const float* pc = (const float*)d_in[0];
    const float* Wf0 = (const float*)d_in[1];
    const float* Wd0 = (const float*)d_in[2];
    const float* g0 = (const float*)d_in[3];
    const float* b0 = (const float*)d_in[4];
    const float* Wf1 = (const float*)d_in[5];
    const float* Wd1 = (const float*)d_in[6];
    const float* g1 = (const float*)d_in[7];
    const float* b1 = (const float*)d_in[8];
    const float* gbn1 = (const float*)d_in[9];
    const float* bbn1 = (const float*)d_in[10];
    const float* Wf2 = (const float*)d_in[11];
    const float* Wd2 = (const float*)d_in[12];
    const float* g2 = (const float*)d_in[13];
    const float* b2 = (const float*)d_in[14];
    float* out = (float*)d_out;

    char* ws = (char*)d_ws;
    double* gws = (double*)ws;
    double* st0 = gws;          // padded slots [0,336)
    double* st1 = gws + 336;    // [336,672)
    double* stB = gws + 672;    // [672,1008)
    double* st2 = gws + 1008;   // [1008,1056)
    double* acc = gws + 1056;   // [1056,2208)  -> 17664 B
    unsigned* cnts = (unsigned*)(ws + 17664);     // 8 counters (32 B)
    int* nbrbest = (int*)(ws + 32768);            // 256 KB
    float* part = (float*)(ws + 294912);          // 42*2048 f32 = 344 KB (shared by stages)
    float* xbuf = (float*)(ws + 655360);          // 63*NPTS f32 = 16.5 MB

    hipMemsetAsync(d_ws, 0, 32768, stream);  // stats + acc + counters

    k_knn<<<NBK, 256, 0, stream>>>(pc, Wf0, nbrbest, part, cnts + 0, st0);
    k_l0st1<<<NBT, 256, 0, stream>>>(pc, nbrbest, Wf0, Wd0, g0, b0, Wf1, st0,
                                     xbuf, part, cnts + 1, st1);
    k_l1stB<<<NBT, 256, 0, stream>>>(xbuf, Wf1, Wd1, g1, b1, st1, part,
                                     cnts + 2, stB);
    k_bn1st2<<<NBT, 256, 0, stream>>>(xbuf, gbn1, bbn1, Wf2, stB, part,
                                      cnts + 3, st2);
    k_accfin<<<NBT, 256, 0, stream>>>(xbuf, Wf2, Wd2, g2, b2, st2, acc,
                                      cnts + 4, out);
}

// Round 8
// 273.688 us; speedup vs baseline: 2.6043x; 2.6043x over previous
//
#include <hip/hip_runtime.h>
#include <math.h>

#define B 16
#define N 4096
#define NPTS (B * N)   // 65536
#define NBK 2048       // knn grid blocks
#define NBT 1024       // tail grid blocks (64 points/block)
#define EPSF 1e-6f
#define S8(i) ((i) * 8)  // 64B-padded double slot

__device__ __forceinline__ float waveReduceSum(float v) {
#pragma unroll
    for (int m = 32; m > 0; m >>= 1) v += __shfl_xor(v, m, 64);
    return v;
}

__device__ __forceinline__ void leaky3(float px, float py, float pz,
                                       float dx, float dy, float dz, float s,
                                       float& ox, float& oy, float& oz) {
    float dotr = px * dx + py * dy + pz * dz;
    float dsq = dx * dx + dy * dy + dz * dz;
    float dot = s * dotr;
    float coef = (dot >= 0.f) ? 0.f : (dot / (dsq + EPSF));
    ox = s * px - coef * dx;
    oy = s * py - coef * dy;
    oz = s * pz - coef * dz;
}

__device__ __forceinline__ void mk_muisd(const double* st, int cnt, double M,
                                         float* smu, float* sisd) {
    const int i = threadIdx.x;
    if (i < cnt) {
        double m = st[S8(i)] / M;
        double v = st[S8(cnt + i)] / M - m * m;
        smu[i] = (float)m;
        sisd[i] = (float)(1.0 / sqrt(v + 1e-5));
    }
}

struct Feat {
    float cx, cy, cz, e0x, e0y, e0z, e2x, e2y, e2z;
};

__device__ __forceinline__ Feat make_feat(const float* __restrict__ pc,
                                          const int* __restrict__ nbr, int pid) {
    const int b = pid >> 12, n = pid & (N - 1);
    const float* base = pc + (size_t)b * (3 * N);
    Feat f;
    f.cx = base[3 * n];
    f.cy = base[3 * n + 1];
    f.cz = base[3 * n + 2];
    const int jn = nbr[pid];
    float nx = base[3 * jn], ny = base[3 * jn + 1], nz = base[3 * jn + 2];
    f.e0x = nx - f.cx;
    f.e0y = ny - f.cy;
    f.e0z = nz - f.cz;
    f.e2x = ny * f.cz - nz * f.cy;
    f.e2y = nz * f.cx - nx * f.cz;
    f.e2z = nx * f.cy - ny * f.cx;
    return f;
}

// ---------------- K1: nearest-other (round-5 branch-free scan) + layer0 BN stats ---
#define QW 8
__global__ __launch_bounds__(256) void k_knn(const float* __restrict__ pc,
                                             const float* __restrict__ Wf0,
                                             int* __restrict__ nbrbest,
                                             double* __restrict__ st0) {
    __shared__ float sx[N], sy[N], sz[N];
    __shared__ float ws0[63], sred[168];
    const int b = blockIdx.x >> 7;
    const int qblk = (blockIdx.x & 127) * 32;
    const float* base = pc + (size_t)b * (N * 3);
    for (int j = threadIdx.x; j < N; j += 256) {
        sx[j] = base[3 * j + 0];
        sy[j] = base[3 * j + 1];
        sz[j] = base[3 * j + 2];
    }
    if (threadIdx.x < 63) ws0[threadIdx.x] = Wf0[threadIdx.x];
    __syncthreads();
    const int wid = threadIdx.x >> 6, lane = threadIdx.x & 63;
    const int q0 = qblk + wid * QW;
    float qx[QW], qy[QW], qz[QW], bv[QW];
    int bi[QW], bq[QW];
#pragma unroll
    for (int q = 0; q < QW; ++q) {
        qx[q] = sx[q0 + q];
        qy[q] = sy[q0 + q];
        qz[q] = sz[q0 + q];
        bv[q] = -3.0e38f;
        bi[q] = 0;
    }
    // branch-free f32 proxy scan (self-test folded in every iteration; proven 73us)
#pragma unroll 4
    for (int ch = 0; ch < N / 64; ++ch) {
        const int j = ch * 64 + lane;
        const float xd = sx[j], yd = sy[j], zd = sz[j];
        const float nr2h = -0.5f * (xd * xd + yd * yd + zd * zd);
#pragma unroll
        for (int q = 0; q < QW; ++q) {
            float pd = fmaf(qx[q], xd, fmaf(qy[q], yd, fmaf(qz[q], zd, nr2h)));
            bool upd = (pd > bv[q]) && (j != q0 + q);
            bv[q] = upd ? pd : bv[q];
            bi[q] = upd ? j : bi[q];
        }
    }
#pragma unroll
    for (int q = 0; q < QW; ++q) {
        // butterfly merge keeping top-2 (value desc, tie -> lower index)
        float a0v = bv[q], a1v = -3.0e38f;
        int a0i = bi[q], a1i = 0x7fffffff;
#pragma unroll
        for (int m = 1; m < 64; m <<= 1) {
            float b0v = __shfl_xor(a0v, m, 64), b1v = __shfl_xor(a1v, m, 64);
            int b0i = __shfl_xor(a0i, m, 64), b1i = __shfl_xor(a1i, m, 64);
            bool bf = (b0v > a0v) || (b0v == a0v && b0i < a0i);
            float c0v = bf ? a0v : b0v;
            int c0i = bf ? a0i : b0i;
            float c1v = bf ? b1v : a1v;
            int c1i = bf ? b1i : a1i;
            a0v = bf ? b0v : a0v;
            a0i = bf ? b0i : a0i;
            bool cf = (c0v > c1v) || (c0v == c1v && c0i < c1i);
            a1v = cf ? c0v : c1v;
            a1i = cf ? c0i : c1i;
        }
        // exact f64 re-score of the two candidates
        const int i0 = a0i, i1 = a1i;
        double dxa = (double)qx[q] - (double)sx[i0];
        double dya = (double)qy[q] - (double)sy[i0];
        double dza = (double)qz[q] - (double)sz[i0];
        double d0 = dxa * dxa + dya * dya + dza * dza;
        double dxb = (double)qx[q] - (double)sx[i1];
        double dyb = (double)qy[q] - (double)sy[i1];
        double dzb = (double)qz[q] - (double)sz[i1];
        double d1 = dxb * dxb + dyb * dyb + dzb * dzb;
        bool take1 = (d1 < d0) || (d1 == d0 && i1 < i0);
        int best = take1 ? i1 : i0;
        bq[q] = best;
        if (lane == 0) nbrbest[(size_t)b * N + q0 + q] = best;
    }
    // ---- fused st0: lane<21 owns channel=lane for this wave's 8 queries ----
    if (lane < 21) {
        float s1 = 0.f, s2 = 0.f;
        const float w0 = ws0[3 * lane], w1 = ws0[3 * lane + 1], w2 = ws0[3 * lane + 2];
#pragma unroll
        for (int q = 0; q < QW; ++q) {
            const int sq = q0 + q, jn = bq[q];
            const float cx = sx[sq], cy = sy[sq], cz = sz[sq];
            const float nx = sx[jn], ny = sy[jn], nz = sz[jn];
            const float e0x = nx - cx, e0y = ny - cy, e0z = nz - cz;
            const float e2x = ny * cz - nz * cy;
            const float e2y = nz * cx - nx * cz;
            const float e2z = nx * cy - ny * cx;
            float pSx = w1 * cx, pSy = w1 * cy, pSz = w1 * cz;
            float nS = sqrtf(pSx * pSx + pSy * pSy + pSz * pSz) + EPSF;
            float px = w0 * e0x + w1 * cx + w2 * e2x;
            float py = w0 * e0y + w1 * cy + w2 * e2y;
            float pz = w0 * e0z + w1 * cz + w2 * e2z;
            float nN = sqrtf(px * px + py * py + pz * pz) + EPSF;
            s1 += nS + nN;
            s2 += nS * nS + nN * nN;
        }
        sred[wid * 42 + lane] = s1;
        sred[wid * 42 + 21 + lane] = s2;
    }
    __syncthreads();
    if (threadIdx.x < 42) {
        float p = sred[threadIdx.x] + sred[42 + threadIdx.x] +
                  sred[84 + threadIdx.x] + sred[126 + threadIdx.x];
        atomicAdd(&st0[S8(threadIdx.x)], (double)p);  // slots: [c]=sum, [21+c]=sumsq
    }
}

// ---------------- K2: layer0 apply -> xbuf + LDS tile, layer1 BN stats --------------
__global__ __launch_bounds__(256) void k_l0st1(
    const float* __restrict__ pc, const int* __restrict__ nbr,
    const float* __restrict__ Wf0, const float* __restrict__ Wd0,
    const float* __restrict__ g0, const float* __restrict__ b0,
    const float* __restrict__ Wf1, const double* __restrict__ st0,
    float* __restrict__ xbuf, double* __restrict__ st1) {
    __shared__ float wf0[63], wd0[63], wf1[441], gg[21], bbs[21], mu[21], isd[21];
    __shared__ float xs[63 * 64];
    if (threadIdx.x < 63) {
        wf0[threadIdx.x] = Wf0[threadIdx.x];
        wd0[threadIdx.x] = Wd0[threadIdx.x];
    }
    for (int i = threadIdx.x; i < 441; i += 256) wf1[i] = Wf1[i];
    if (threadIdx.x < 21) {
        gg[threadIdx.x] = g0[threadIdx.x];
        bbs[threadIdx.x] = b0[threadIdx.x];
    }
    mk_muisd(st0, 21, (double)NPTS * 2.0, mu, isd);
    __syncthreads();
    const int lane = threadIdx.x & 63, grp = threadIdx.x >> 6;
    const int pid = blockIdx.x * 64 + lane;
    Feat f = make_feat(pc, nbr, pid);
    const int cbase = grp * 6;
#pragma unroll
    for (int k = 0; k < 6; ++k) {
        const int c = cbase + k;
        if (c >= 21) break;
        float w0 = wf0[3 * c], w1 = wf0[3 * c + 1], w2 = wf0[3 * c + 2];
        float u0 = wd0[3 * c], u1 = wd0[3 * c + 1], u2 = wd0[3 * c + 2];
        float pSx = w1 * f.cx, pSy = w1 * f.cy, pSz = w1 * f.cz;
        float nS = sqrtf(pSx * pSx + pSy * pSy + pSz * pSz) + EPSF;
        float sS = ((nS - mu[c]) * isd[c] * gg[c] + bbs[c]) / nS;
        float oSx, oSy, oSz;
        leaky3(pSx, pSy, pSz, u1 * f.cx, u1 * f.cy, u1 * f.cz, sS, oSx, oSy, oSz);
        float px = w0 * f.e0x + w1 * f.cx + w2 * f.e2x;
        float py = w0 * f.e0y + w1 * f.cy + w2 * f.e2y;
        float pz = w0 * f.e0z + w1 * f.cz + w2 * f.e2z;
        float dx = u0 * f.e0x + u1 * f.cx + u2 * f.e2x;
        float dy = u0 * f.e0y + u1 * f.cy + u2 * f.e2y;
        float dz = u0 * f.e0z + u1 * f.cz + u2 * f.e2z;
        float nN = sqrtf(px * px + py * py + pz * pz) + EPSF;
        float sN = ((nN - mu[c]) * isd[c] * gg[c] + bbs[c]) / nN;
        float oNx, oNy, oNz;
        leaky3(px, py, pz, dx, dy, dz, sN, oNx, oNy, oNz);
        float x0 = 0.5f * (oSx + oNx), x1 = 0.5f * (oSy + oNy), x2 = 0.5f * (oSz + oNz);
        xs[(3 * c + 0) * 64 + lane] = x0;
        xs[(3 * c + 1) * 64 + lane] = x1;
        xs[(3 * c + 2) * 64 + lane] = x2;
        xbuf[(size_t)(3 * c + 0) * NPTS + pid] = x0;
        xbuf[(size_t)(3 * c + 1) * NPTS + pid] = x1;
        xbuf[(size_t)(3 * c + 2) * NPTS + pid] = x2;
    }
    __syncthreads();
    float xl[63];
#pragma unroll
    for (int ff = 0; ff < 63; ++ff) xl[ff] = xs[ff * 64 + lane];
#pragma unroll
    for (int k = 0; k < 6; ++k) {
        const int c = cbase + k;
        if (c >= 21) break;
        float p0 = 0.f, p1 = 0.f, p2 = 0.f;
#pragma unroll
        for (int j = 0; j < 21; ++j) {
            float w = wf1[c * 21 + j];
            p0 = fmaf(w, xl[3 * j + 0], p0);
            p1 = fmaf(w, xl[3 * j + 1], p1);
            p2 = fmaf(w, xl[3 * j + 2], p2);
        }
        float nn = sqrtf(p0 * p0 + p1 * p1 + p2 * p2) + EPSF;
        float r1 = waveReduceSum(nn);
        float r2 = waveReduceSum(nn * nn);
        if (lane == 0) {
            atomicAdd(&st1[S8(c)], (double)r1);
            atomicAdd(&st1[S8(21 + c)], (double)r2);
        }
    }
}

// ---------------- K3: layer1 apply (in-place) + bn1 stats ---------------------------
__global__ __launch_bounds__(256) void k_l1stB(
    float* __restrict__ xbuf, const float* __restrict__ Wf1,
    const float* __restrict__ Wd1, const float* __restrict__ g1,
    const float* __restrict__ b1, const double* __restrict__ st1,
    double* __restrict__ stB) {
    __shared__ float wf1[441], wd1[441], gg[21], bbs[21], mu[21], isd[21];
    for (int i = threadIdx.x; i < 441; i += 256) {
        wf1[i] = Wf1[i];
        wd1[i] = Wd1[i];
    }
    if (threadIdx.x < 21) {
        gg[threadIdx.x] = g1[threadIdx.x];
        bbs[threadIdx.x] = b1[threadIdx.x];
    }
    mk_muisd(st1, 21, (double)NPTS, mu, isd);
    __syncthreads();
    const int lane = threadIdx.x & 63, grp = threadIdx.x >> 6;
    const int pid = blockIdx.x * 64 + lane;
    float xl[63];
#pragma unroll
    for (int ff = 0; ff < 63; ++ff) xl[ff] = xbuf[(size_t)ff * NPTS + pid];
    __syncthreads();  // all reads before any in-place write (pid columns block-local)
    const int cbase = grp * 6;
#pragma unroll
    for (int k = 0; k < 6; ++k) {
        const int c = cbase + k;
        if (c >= 21) break;
        float p0 = 0.f, p1 = 0.f, p2 = 0.f, d0 = 0.f, d1 = 0.f, d2 = 0.f;
#pragma unroll
        for (int j = 0; j < 21; ++j) {
            float w = wf1[c * 21 + j], u = wd1[c * 21 + j];
            p0 = fmaf(w, xl[3 * j + 0], p0);
            p1 = fmaf(w, xl[3 * j + 1], p1);
            p2 = fmaf(w, xl[3 * j + 2], p2);
            d0 = fmaf(u, xl[3 * j + 0], d0);
            d1 = fmaf(u, xl[3 * j + 1], d1);
            d2 = fmaf(u, xl[3 * j + 2], d2);
        }
        float nn = sqrtf(p0 * p0 + p1 * p1 + p2 * p2) + EPSF;
        float s = ((nn - mu[c]) * isd[c] * gg[c] + bbs[c]) / nn;
        float ox, oy, oz;
        leaky3(p0, p1, p2, d0, d1, d2, s, ox, oy, oz);
        xbuf[(size_t)(3 * c + 0) * NPTS + pid] = ox;
        xbuf[(size_t)(3 * c + 1) * NPTS + pid] = oy;
        xbuf[(size_t)(3 * c + 2) * NPTS + pid] = oz;
        float on = sqrtf(ox * ox + oy * oy + oz * oz) + EPSF;
        float r1 = waveReduceSum(on);
        float r2 = waveReduceSum(on * on);
        if (lane == 0) {
            atomicAdd(&stB[S8(c)], (double)r1);
            atomicAdd(&stB[S8(21 + c)], (double)r2);
        }
    }
}

// ---------------- K4: bn1 apply (in-place) + layer2 BN stats ------------------------
__global__ __launch_bounds__(256) void k_bn1st2(
    float* __restrict__ xbuf, const float* __restrict__ gbn,
    const float* __restrict__ bbn, const float* __restrict__ Wf2,
    const double* __restrict__ stB, double* __restrict__ st2) {
    __shared__ float wf2[63], gg[21], bbs[21], mu[21], isd[21];
    __shared__ float zs[63 * 64];
    if (threadIdx.x < 63) wf2[threadIdx.x] = Wf2[threadIdx.x];
    if (threadIdx.x < 21) {
        gg[threadIdx.x] = gbn[threadIdx.x];
        bbs[threadIdx.x] = bbn[threadIdx.x];
    }
    mk_muisd(stB, 21, (double)NPTS, mu, isd);
    __syncthreads();
    const int lane = threadIdx.x & 63, grp = threadIdx.x >> 6;
    const int pid = blockIdx.x * 64 + lane;
    const int cbase = grp * 6;
#pragma unroll
    for (int k = 0; k < 6; ++k) {
        const int c = cbase + k;
        if (c >= 21) break;
        float y0 = xbuf[(size_t)(3 * c + 0) * NPTS + pid];
        float y1 = xbuf[(size_t)(3 * c + 1) * NPTS + pid];
        float y2 = xbuf[(size_t)(3 * c + 2) * NPTS + pid];
        float nn = sqrtf(y0 * y0 + y1 * y1 + y2 * y2) + EPSF;
        float sc = ((nn - mu[c]) * isd[c] * gg[c] + bbs[c]) / nn;
        y0 *= sc; y1 *= sc; y2 *= sc;
        zs[(3 * c + 0) * 64 + lane] = y0;
        zs[(3 * c + 1) * 64 + lane] = y1;
        zs[(3 * c + 2) * 64 + lane] = y2;
        xbuf[(size_t)(3 * c + 0) * NPTS + pid] = y0;
        xbuf[(size_t)(3 * c + 1) * NPTS + pid] = y1;
        xbuf[(size_t)(3 * c + 2) * NPTS + pid] = y2;
    }
    __syncthreads();
    if (grp < 3) {
        float p0 = 0.f, p1 = 0.f, p2 = 0.f;
#pragma unroll
        for (int j = 0; j < 21; ++j) {
            float w = wf2[grp * 21 + j];
            p0 = fmaf(w, zs[(3 * j + 0) * 64 + lane], p0);
            p1 = fmaf(w, zs[(3 * j + 1) * 64 + lane], p1);
            p2 = fmaf(w, zs[(3 * j + 2) * 64 + lane], p2);
        }
        float nn = sqrtf(p0 * p0 + p1 * p1 + p2 * p2) + EPSF;
        float r1 = waveReduceSum(nn);
        float r2 = waveReduceSum(nn * nn);
        if (lane == 0) {
            atomicAdd(&st2[S8(grp)], (double)r1);
            atomicAdd(&st2[S8(3 + grp)], (double)r2);
        }
    }
}

// ---------------- K5: layer2 apply + per-batch reduce ------------------------------
__global__ __launch_bounds__(256) void k_acc(
    const float* __restrict__ xbuf, const float* __restrict__ Wf2,
    const float* __restrict__ Wd2, const float* __restrict__ g2,
    const float* __restrict__ b2, const double* __restrict__ st2,
    double* __restrict__ acc) {
    __shared__ float wf2[63], wd2[63], gg[3], bbs[3], mu[3], isd[3];
    if (threadIdx.x < 63) {
        wf2[threadIdx.x] = Wf2[threadIdx.x];
        wd2[threadIdx.x] = Wd2[threadIdx.x];
    }
    if (threadIdx.x < 3) {
        gg[threadIdx.x] = g2[threadIdx.x];
        bbs[threadIdx.x] = b2[threadIdx.x];
    }
    mk_muisd(st2, 3, (double)NPTS, mu, isd);
    __syncthreads();
    const int lane = threadIdx.x & 63, grp = threadIdx.x >> 6;
    if (grp >= 3) return;
    const int pid = blockIdx.x * 64 + lane;
    const int b = pid >> 12;
    float p0 = 0.f, p1 = 0.f, p2 = 0.f, d0 = 0.f, d1 = 0.f, d2 = 0.f;
#pragma unroll
    for (int j = 0; j < 21; ++j) {
        float x0 = xbuf[(size_t)(3 * j + 0) * NPTS + pid];
        float x1 = xbuf[(size_t)(3 * j + 1) * NPTS + pid];
        float x2 = xbuf[(size_t)(3 * j + 2) * NPTS + pid];
        float w = wf2[grp * 21 + j], u = wd2[grp * 21 + j];
        p0 = fmaf(w, x0, p0);
        p1 = fmaf(w, x1, p1);
        p2 = fmaf(w, x2, p2);
        d0 = fmaf(u, x0, d0);
        d1 = fmaf(u, x1, d1);
        d2 = fmaf(u, x2, d2);
    }
    float nn = sqrtf(p0 * p0 + p1 * p1 + p2 * p2) + EPSF;
    float s = ((nn - mu[grp]) * isd[grp] * gg[grp] + bbs[grp]) / nn;
    float ox, oy, oz;
    leaky3(p0, p1, p2, d0, d1, d2, s, ox, oy, oz);
    float rx = waveReduceSum(ox);
    float ry = waveReduceSum(oy);
    float rz = waveReduceSum(oz);
    if (lane == 0) {
        atomicAdd(&acc[S8(b * 9 + grp * 3 + 0)], (double)rx);
        atomicAdd(&acc[S8(b * 9 + grp * 3 + 1)], (double)ry);
        atomicAdd(&acc[S8(b * 9 + grp * 3 + 2)], (double)rz);
    }
}

// ---------------- K6: finalize ------------------------------------------------------
__global__ void k_fin(const double* __restrict__ acc, float* __restrict__ out) {
    if (threadIdx.x < B * 9)
        out[threadIdx.x] = (float)(acc[S8(threadIdx.x)] * (1.0 / (double)N));
}

extern "C" void kernel_launch(void* const* d_in, const int* in_sizes, int n_in,
                              void* d_out, int out_size, void* d_ws, size_t ws_size,
                              hipStream_t stream) {
    const float* pc = (const float*)d_in[0];
    const float* Wf0 = (const float*)d_in[1];
    const float* Wd0 = (const float*)d_in[2];
    const float* g0 = (const float*)d_in[3];
    const float* b0 = (const float*)d_in[4];
    const float* Wf1 = (const float*)d_in[5];
    const float* Wd1 = (const float*)d_in[6];
    const float* g1 = (const float*)d_in[7];
    const float* b1 = (const float*)d_in[8];
    const float* gbn1 = (const float*)d_in[9];
    const float* bbn1 = (const float*)d_in[10];
    const float* Wf2 = (const float*)d_in[11];
    const float* Wd2 = (const float*)d_in[12];
    const float* g2 = (const float*)d_in[13];
    const float* b2 = (const float*)d_in[14];
    float* out = (float*)d_out;

    char* ws = (char*)d_ws;
    double* gws = (double*)ws;
    double* st0 = gws;          // padded slots [0,336)
    double* st1 = gws + 336;    // [336,672)
    double* stB = gws + 672;    // [672,1008)
    double* st2 = gws + 1008;   // [1008,1056)
    double* acc = gws + 1056;   // [1056,2208)  -> 17664 B
    int* nbrbest = (int*)(ws + 32768);            // 256 KB
    float* xbuf = (float*)(ws + 32768 + 262144);  // 63*NPTS f32 = 16.5 MB

    hipMemsetAsync(d_ws, 0, 17664, stream);  // zero stats + acc

    k_knn<<<NBK, 256, 0, stream>>>(pc, Wf0, nbrbest, st0);
    k_l0st1<<<NBT, 256, 0, stream>>>(pc, nbrbest, Wf0, Wd0, g0, b0, Wf1, st0,
                                     xbuf, st1);
    k_l1stB<<<NBT, 256, 0, stream>>>(xbuf, Wf1, Wd1, g1, b1, st1, stB);
    k_bn1st2<<<NBT, 256, 0, stream>>>(xbuf, gbn1, bbn1, Wf2, stB, st2);
    k_acc<<<NBT, 256, 0, stream>>>(xbuf, Wf2, Wd2, g2, b2, st2, acc);
    k_fin<<<1, 256, 0, stream>>>(acc, out);
}

// Round 10
// 222.711 us; speedup vs baseline: 3.2003x; 1.2289x over previous
//
#include <hip/hip_runtime.h>
#include <math.h>

#define B 16
#define N 4096
#define NPTS (B * N)   // 65536
#define NBK 2048       // knn grid blocks (128 per batch)
#define NBT 1024       // tail grid blocks (64 points/block, 64 per batch)
#define EPSF 1e-6f
#define S8(i) ((i) * 8)  // 64B-padded double slot

__device__ __forceinline__ float waveReduceSum(float v) {
#pragma unroll
    for (int m = 32; m > 0; m >>= 1) v += __shfl_xor(v, m, 64);
    return v;
}

__device__ __forceinline__ void leaky3(float px, float py, float pz,
                                       float dx, float dy, float dz, float s,
                                       float& ox, float& oy, float& oz) {
    float dotr = px * dx + py * dy + pz * dz;
    float dsq = dx * dx + dy * dy + dz * dz;
    float dot = s * dotr;
    float coef = (dot >= 0.f) ? 0.f : (dot / (dsq + EPSF));
    ox = s * px - coef * dx;
    oy = s * py - coef * dy;
    oz = s * pz - coef * dz;
}

// Batched stats: slot (b*2*cnt + i) = sum_i of batch b, (b*2*cnt + cnt + i) = sumsq.
// Consumer sums the 16 batch partials (f64) then forms mu / 1/sqrt(var+eps).
__device__ __forceinline__ void mk_muisd_b(const double* st, int cnt, double M,
                                           float* smu, float* sisd) {
    const int i = threadIdx.x;
    if (i < cnt) {
        double s1 = 0.0, s2 = 0.0;
#pragma unroll
        for (int b = 0; b < B; ++b) {
            s1 += st[S8(b * 2 * cnt + i)];
            s2 += st[S8(b * 2 * cnt + cnt + i)];
        }
        double m = s1 / M;
        double v = s2 / M - m * m;
        smu[i] = (float)m;
        sisd[i] = (float)(1.0 / sqrt(v + 1e-5));
    }
}

struct Feat {
    float cx, cy, cz, e0x, e0y, e0z, e2x, e2y, e2z;
};

__device__ __forceinline__ Feat make_feat(const float* __restrict__ pc,
                                          const int* __restrict__ nbr, int pid) {
    const int b = pid >> 12, n = pid & (N - 1);
    const float* base = pc + (size_t)b * (3 * N);
    Feat f;
    f.cx = base[3 * n];
    f.cy = base[3 * n + 1];
    f.cz = base[3 * n + 2];
    const int jn = nbr[pid];
    float nx = base[3 * jn], ny = base[3 * jn + 1], nz = base[3 * jn + 2];
    f.e0x = nx - f.cx;
    f.e0y = ny - f.cy;
    f.e0z = nz - f.cz;
    f.e2x = ny * f.cz - nz * f.cy;
    f.e2y = nz * f.cx - nx * f.cz;
    f.e2z = nx * f.cy - ny * f.cx;
    return f;
}

// ---------------- K1: nearest-other (branch-free scan) + layer0 BN stats -----------
#define QW 8
__global__ __launch_bounds__(256) void k_knn(const float* __restrict__ pc,
                                             const float* __restrict__ Wf0,
                                             int* __restrict__ nbrbest,
                                             double* __restrict__ st0) {
    __shared__ float sx[N], sy[N], sz[N];
    __shared__ float ws0[63], sred[168];
    const int b = blockIdx.x >> 7;
    const int qblk = (blockIdx.x & 127) * 32;
    const float* base = pc + (size_t)b * (N * 3);
    for (int j = threadIdx.x; j < N; j += 256) {
        sx[j] = base[3 * j + 0];
        sy[j] = base[3 * j + 1];
        sz[j] = base[3 * j + 2];
    }
    if (threadIdx.x < 63) ws0[threadIdx.x] = Wf0[threadIdx.x];
    __syncthreads();
    const int wid = threadIdx.x >> 6, lane = threadIdx.x & 63;
    const int q0 = qblk + wid * QW;
    float qx[QW], qy[QW], qz[QW], bv[QW];
    int bi[QW], bq[QW];
#pragma unroll
    for (int q = 0; q < QW; ++q) {
        qx[q] = sx[q0 + q];
        qy[q] = sy[q0 + q];
        qz[q] = sz[q0 + q];
        bv[q] = -3.0e38f;
        bi[q] = 0;
    }
    // branch-free f32 proxy scan (self-test folded into every iteration)
#pragma unroll 4
    for (int ch = 0; ch < N / 64; ++ch) {
        const int j = ch * 64 + lane;
        const float xd = sx[j], yd = sy[j], zd = sz[j];
        const float nr2h = -0.5f * (xd * xd + yd * yd + zd * zd);
#pragma unroll
        for (int q = 0; q < QW; ++q) {
            float pd = fmaf(qx[q], xd, fmaf(qy[q], yd, fmaf(qz[q], zd, nr2h)));
            bool upd = (pd > bv[q]) && (j != q0 + q);
            bv[q] = upd ? pd : bv[q];
            bi[q] = upd ? j : bi[q];
        }
    }
#pragma unroll
    for (int q = 0; q < QW; ++q) {
        // butterfly merge keeping top-2 (value desc, tie -> lower index)
        float a0v = bv[q], a1v = -3.0e38f;
        int a0i = bi[q], a1i = 0x7fffffff;
#pragma unroll
        for (int m = 1; m < 64; m <<= 1) {
            float b0v = __shfl_xor(a0v, m, 64), b1v = __shfl_xor(a1v, m, 64);
            int b0i = __shfl_xor(a0i, m, 64), b1i = __shfl_xor(a1i, m, 64);
            bool bf = (b0v > a0v) || (b0v == a0v && b0i < a0i);
            float c0v = bf ? a0v : b0v;
            int c0i = bf ? a0i : b0i;
            float c1v = bf ? b1v : a1v;
            int c1i = bf ? b1i : a1i;
            a0v = bf ? b0v : a0v;
            a0i = bf ? b0i : a0i;
            bool cf = (c0v > c1v) || (c0v == c1v && c0i < c1i);
            a1v = cf ? c0v : c1v;
            a1i = cf ? c0i : c1i;
        }
        // exact f64 re-score of the two candidates
        const int i0 = a0i, i1 = a1i;
        double dxa = (double)qx[q] - (double)sx[i0];
        double dya = (double)qy[q] - (double)sy[i0];
        double dza = (double)qz[q] - (double)sz[i0];
        double d0 = dxa * dxa + dya * dya + dza * dza;
        double dxb = (double)qx[q] - (double)sx[i1];
        double dyb = (double)qy[q] - (double)sy[i1];
        double dzb = (double)qz[q] - (double)sz[i1];
        double d1 = dxb * dxb + dyb * dyb + dzb * dzb;
        bool take1 = (d1 < d0) || (d1 == d0 && i1 < i0);
        int best = take1 ? i1 : i0;
        bq[q] = best;
        if (lane == 0) nbrbest[(size_t)b * N + q0 + q] = best;
    }
    // ---- fused st0: lane<21 owns channel=lane for this wave's 8 queries ----
    if (lane < 21) {
        float s1 = 0.f, s2 = 0.f;
        const float w0 = ws0[3 * lane], w1 = ws0[3 * lane + 1], w2 = ws0[3 * lane + 2];
#pragma unroll
        for (int q = 0; q < QW; ++q) {
            const int sq = q0 + q, jn = bq[q];
            const float cx = sx[sq], cy = sy[sq], cz = sz[sq];
            const float nx = sx[jn], ny = sy[jn], nz = sz[jn];
            const float e0x = nx - cx, e0y = ny - cy, e0z = nz - cz;
            const float e2x = ny * cz - nz * cy;
            const float e2y = nz * cx - nx * cz;
            const float e2z = nx * cy - ny * cx;
            float pSx = w1 * cx, pSy = w1 * cy, pSz = w1 * cz;
            float nS = sqrtf(pSx * pSx + pSy * pSy + pSz * pSz) + EPSF;
            float px = w0 * e0x + w1 * cx + w2 * e2x;
            float py = w0 * e0y + w1 * cy + w2 * e2y;
            float pz = w0 * e0z + w1 * cz + w2 * e2z;
            float nN = sqrtf(px * px + py * py + pz * pz) + EPSF;
            s1 += nS + nN;
            s2 += nS * nS + nN * nN;
        }
        sred[wid * 42 + lane] = s1;
        sred[wid * 42 + 21 + lane] = s2;
    }
    __syncthreads();
    if (threadIdx.x < 42) {
        float p = sred[threadIdx.x] + sred[42 + threadIdx.x] +
                  sred[84 + threadIdx.x] + sred[126 + threadIdx.x];
        // per-batch slot: only 128 atomics per address
        atomicAdd(&st0[S8(b * 42 + threadIdx.x)], (double)p);
    }
}

// ---------------- K2: layer0 apply -> xbuf + LDS tile, layer1 BN stats --------------
__global__ __launch_bounds__(256) void k_l0st1(
    const float* __restrict__ pc, const int* __restrict__ nbr,
    const float* __restrict__ Wf0, const float* __restrict__ Wd0,
    const float* __restrict__ g0, const float* __restrict__ b0,
    const float* __restrict__ Wf1, const double* __restrict__ st0,
    float* __restrict__ xbuf, double* __restrict__ st1) {
    __shared__ float wf0[63], wd0[63], wf1[441], gg[21], bbs[21], mu[21], isd[21];
    __shared__ float xs[63 * 64];
    if (threadIdx.x < 63) {
        wf0[threadIdx.x] = Wf0[threadIdx.x];
        wd0[threadIdx.x] = Wd0[threadIdx.x];
    }
    for (int i = threadIdx.x; i < 441; i += 256) wf1[i] = Wf1[i];
    if (threadIdx.x < 21) {
        gg[threadIdx.x] = g0[threadIdx.x];
        bbs[threadIdx.x] = b0[threadIdx.x];
    }
    mk_muisd_b(st0, 21, (double)NPTS * 2.0, mu, isd);
    __syncthreads();
    const int lane = threadIdx.x & 63, grp = threadIdx.x >> 6;
    const int pid = blockIdx.x * 64 + lane;
    const int bb = blockIdx.x >> 6;
    Feat f = make_feat(pc, nbr, pid);
    const int cbase = grp * 6;
#pragma unroll
    for (int k = 0; k < 6; ++k) {
        const int c = cbase + k;
        if (c >= 21) break;
        float w0 = wf0[3 * c], w1 = wf0[3 * c + 1], w2 = wf0[3 * c + 2];
        float u0 = wd0[3 * c], u1 = wd0[3 * c + 1], u2 = wd0[3 * c + 2];
        float pSx = w1 * f.cx, pSy = w1 * f.cy, pSz = w1 * f.cz;
        float nS = sqrtf(pSx * pSx + pSy * pSy + pSz * pSz) + EPSF;
        float sS = ((nS - mu[c]) * isd[c] * gg[c] + bbs[c]) / nS;
        float oSx, oSy, oSz;
        leaky3(pSx, pSy, pSz, u1 * f.cx, u1 * f.cy, u1 * f.cz, sS, oSx, oSy, oSz);
        float px = w0 * f.e0x + w1 * f.cx + w2 * f.e2x;
        float py = w0 * f.e0y + w1 * f.cy + w2 * f.e2y;
        float pz = w0 * f.e0z + w1 * f.cz + w2 * f.e2z;
        float dx = u0 * f.e0x + u1 * f.cx + u2 * f.e2x;
        float dy = u0 * f.e0y + u1 * f.cy + u2 * f.e2y;
        float dz = u0 * f.e0z + u1 * f.cz + u2 * f.e2z;
        float nN = sqrtf(px * px + py * py + pz * pz) + EPSF;
        float sN = ((nN - mu[c]) * isd[c] * gg[c] + bbs[c]) / nN;
        float oNx, oNy, oNz;
        leaky3(px, py, pz, dx, dy, dz, sN, oNx, oNy, oNz);
        float x0 = 0.5f * (oSx + oNx), x1 = 0.5f * (oSy + oNy), x2 = 0.5f * (oSz + oNz);
        xs[(3 * c + 0) * 64 + lane] = x0;
        xs[(3 * c + 1) * 64 + lane] = x1;
        xs[(3 * c + 2) * 64 + lane] = x2;
        xbuf[(size_t)(3 * c + 0) * NPTS + pid] = x0;
        xbuf[(size_t)(3 * c + 1) * NPTS + pid] = x1;
        xbuf[(size_t)(3 * c + 2) * NPTS + pid] = x2;
    }
    __syncthreads();
    float xl[63];
#pragma unroll
    for (int ff = 0; ff < 63; ++ff) xl[ff] = xs[ff * 64 + lane];
#pragma unroll
    for (int k = 0; k < 6; ++k) {
        const int c = cbase + k;
        if (c >= 21) break;
        float p0 = 0.f, p1 = 0.f, p2 = 0.f;
#pragma unroll
        for (int j = 0; j < 21; ++j) {
            float w = wf1[c * 21 + j];
            p0 = fmaf(w, xl[3 * j + 0], p0);
            p1 = fmaf(w, xl[3 * j + 1], p1);
            p2 = fmaf(w, xl[3 * j + 2], p2);
        }
        float nn = sqrtf(p0 * p0 + p1 * p1 + p2 * p2) + EPSF;
        float r1 = waveReduceSum(nn);
        float r2 = waveReduceSum(nn * nn);
        if (lane == 0) {
            atomicAdd(&st1[S8(bb * 42 + c)], (double)r1);
            atomicAdd(&st1[S8(bb * 42 + 21 + c)], (double)r2);
        }
    }
}

// ---------------- K3: layer1 apply (in-place) + bn1 stats ---------------------------
__global__ __launch_bounds__(256) void k_l1stB(
    float* __restrict__ xbuf, const float* __restrict__ Wf1,
    const float* __restrict__ Wd1, const float* __restrict__ g1,
    const float* __restrict__ b1, const double* __restrict__ st1,
    double* __restrict__ stB) {
    __shared__ float wf1[441], wd1[441], gg[21], bbs[21], mu[21], isd[21];
    for (int i = threadIdx.x; i < 441; i += 256) {
        wf1[i] = Wf1[i];
        wd1[i] = Wd1[i];
    }
    if (threadIdx.x < 21) {
        gg[threadIdx.x] = g1[threadIdx.x];
        bbs[threadIdx.x] = b1[threadIdx.x];
    }
    mk_muisd_b(st1, 21, (double)NPTS, mu, isd);
    __syncthreads();
    const int lane = threadIdx.x & 63, grp = threadIdx.x >> 6;
    const int pid = blockIdx.x * 64 + lane;
    const int bb = blockIdx.x >> 6;
    float xl[63];
#pragma unroll
    for (int ff = 0; ff < 63; ++ff) xl[ff] = xbuf[(size_t)ff * NPTS + pid];
    __syncthreads();  // all reads before any in-place write (pid columns block-local)
    const int cbase = grp * 6;
#pragma unroll
    for (int k = 0; k < 6; ++k) {
        const int c = cbase + k;
        if (c >= 21) break;
        float p0 = 0.f, p1 = 0.f, p2 = 0.f, d0 = 0.f, d1 = 0.f, d2 = 0.f;
#pragma unroll
        for (int j = 0; j < 21; ++j) {
            float w = wf1[c * 21 + j], u = wd1[c * 21 + j];
            p0 = fmaf(w, xl[3 * j + 0], p0);
            p1 = fmaf(w, xl[3 * j + 1], p1);
            p2 = fmaf(w, xl[3 * j + 2], p2);
            d0 = fmaf(u, xl[3 * j + 0], d0);
            d1 = fmaf(u, xl[3 * j + 1], d1);
            d2 = fmaf(u, xl[3 * j + 2], d2);
        }
        float nn = sqrtf(p0 * p0 + p1 * p1 + p2 * p2) + EPSF;
        float s = ((nn - mu[c]) * isd[c] * gg[c] + bbs[c]) / nn;
        float ox, oy, oz;
        leaky3(p0, p1, p2, d0, d1, d2, s, ox, oy, oz);
        xbuf[(size_t)(3 * c + 0) * NPTS + pid] = ox;
        xbuf[(size_t)(3 * c + 1) * NPTS + pid] = oy;
        xbuf[(size_t)(3 * c + 2) * NPTS + pid] = oz;
        float on = sqrtf(ox * ox + oy * oy + oz * oz) + EPSF;
        float r1 = waveReduceSum(on);
        float r2 = waveReduceSum(on * on);
        if (lane == 0) {
            atomicAdd(&stB[S8(bb * 42 + c)], (double)r1);
            atomicAdd(&stB[S8(bb * 42 + 21 + c)], (double)r2);
        }
    }
}

// ---------------- K4: bn1 (registers only) + layer2 BN stats — NO writeback ---------
__global__ __launch_bounds__(256) void k_bn1st2(
    const float* __restrict__ xbuf, const float* __restrict__ gbn,
    const float* __restrict__ bbn, const float* __restrict__ Wf2,
    const double* __restrict__ stB, double* __restrict__ st2) {
    __shared__ float wf2[63], gg[21], bbs[21], mu[21], isd[21];
    __shared__ float zs[63 * 64];
    if (threadIdx.x < 63) wf2[threadIdx.x] = Wf2[threadIdx.x];
    if (threadIdx.x < 21) {
        gg[threadIdx.x] = gbn[threadIdx.x];
        bbs[threadIdx.x] = bbn[threadIdx.x];
    }
    mk_muisd_b(stB, 21, (double)NPTS, mu, isd);
    __syncthreads();
    const int lane = threadIdx.x & 63, grp = threadIdx.x >> 6;
    const int pid = blockIdx.x * 64 + lane;
    const int bb = blockIdx.x >> 6;
    const int cbase = grp * 6;
#pragma unroll
    for (int k = 0; k < 6; ++k) {
        const int c = cbase + k;
        if (c >= 21) break;
        float y0 = xbuf[(size_t)(3 * c + 0) * NPTS + pid];
        float y1 = xbuf[(size_t)(3 * c + 1) * NPTS + pid];
        float y2 = xbuf[(size_t)(3 * c + 2) * NPTS + pid];
        float nn = sqrtf(y0 * y0 + y1 * y1 + y2 * y2) + EPSF;
        float sc = ((nn - mu[c]) * isd[c] * gg[c] + bbs[c]) / nn;
        zs[(3 * c + 0) * 64 + lane] = sc * y0;
        zs[(3 * c + 1) * 64 + lane] = sc * y1;
        zs[(3 * c + 2) * 64 + lane] = sc * y2;
    }
    __syncthreads();
    if (grp < 3) {
        float p0 = 0.f, p1 = 0.f, p2 = 0.f;
#pragma unroll
        for (int j = 0; j < 21; ++j) {
            float w = wf2[grp * 21 + j];
            p0 = fmaf(w, zs[(3 * j + 0) * 64 + lane], p0);
            p1 = fmaf(w, zs[(3 * j + 1) * 64 + lane], p1);
            p2 = fmaf(w, zs[(3 * j + 2) * 64 + lane], p2);
        }
        float nn = sqrtf(p0 * p0 + p1 * p1 + p2 * p2) + EPSF;
        float r1 = waveReduceSum(nn);
        float r2 = waveReduceSum(nn * nn);
        if (lane == 0) {
            atomicAdd(&st2[S8(bb * 6 + grp)], (double)r1);
            atomicAdd(&st2[S8(bb * 6 + 3 + grp)], (double)r2);
        }
    }
}

// ---------------- K5: bn1 (recompute) + layer2 apply + per-batch reduce -------------
__global__ __launch_bounds__(256) void k_acc(
    const float* __restrict__ xbuf, const float* __restrict__ gbn,
    const float* __restrict__ bbn, const float* __restrict__ Wf2,
    const float* __restrict__ Wd2, const float* __restrict__ g2,
    const float* __restrict__ b2, const double* __restrict__ stB,
    const double* __restrict__ st2, double* __restrict__ acc) {
    __shared__ float wf2[63], wd2[63], gg[3], bbs[3];
    __shared__ float muB[21], isdB[21], gB[21], bB[21], mu2[3], isd2[3];
    if (threadIdx.x < 63) {
        wf2[threadIdx.x] = Wf2[threadIdx.x];
        wd2[threadIdx.x] = Wd2[threadIdx.x];
    }
    if (threadIdx.x < 21) {
        gB[threadIdx.x] = gbn[threadIdx.x];
        bB[threadIdx.x] = bbn[threadIdx.x];
    }
    if (threadIdx.x < 3) {
        gg[threadIdx.x] = g2[threadIdx.x];
        bbs[threadIdx.x] = b2[threadIdx.x];
    }
    mk_muisd_b(stB, 21, (double)NPTS, muB, isdB);
    mk_muisd_b(st2, 3, (double)NPTS, mu2, isd2);
    __syncthreads();
    const int lane = threadIdx.x & 63, grp = threadIdx.x >> 6;
    if (grp >= 3) return;
    const int pid = blockIdx.x * 64 + lane;
    const int bb = pid >> 12;
    float p0 = 0.f, p1 = 0.f, p2 = 0.f, d0 = 0.f, d1 = 0.f, d2 = 0.f;
#pragma unroll
    for (int j = 0; j < 21; ++j) {
        float y0 = xbuf[(size_t)(3 * j + 0) * NPTS + pid];
        float y1 = xbuf[(size_t)(3 * j + 1) * NPTS + pid];
        float y2 = xbuf[(size_t)(3 * j + 2) * NPTS + pid];
        float nn = sqrtf(y0 * y0 + y1 * y1 + y2 * y2) + EPSF;
        float sc = ((nn - muB[j]) * isdB[j] * gB[j] + bB[j]) / nn;
        float z0 = sc * y0, z1 = sc * y1, z2 = sc * y2;
        float w = wf2[grp * 21 + j], u = wd2[grp * 21 + j];
        p0 = fmaf(w, z0, p0);
        p1 = fmaf(w, z1, p1);
        p2 = fmaf(w, z2, p2);
        d0 = fmaf(u, z0, d0);
        d1 = fmaf(u, z1, d1);
        d2 = fmaf(u, z2, d2);
    }
    float nn = sqrtf(p0 * p0 + p1 * p1 + p2 * p2) + EPSF;
    float s = ((nn - mu2[grp]) * isd2[grp] * gg[grp] + bbs[grp]) / nn;
    float ox, oy, oz;
    leaky3(p0, p1, p2, d0, d1, d2, s, ox, oy, oz);
    float rx = waveReduceSum(ox);
    float ry = waveReduceSum(oy);
    float rz = waveReduceSum(oz);
    if (lane == 0) {
        atomicAdd(&acc[S8(bb * 9 + grp * 3 + 0)], (double)rx);
        atomicAdd(&acc[S8(bb * 9 + grp * 3 + 1)], (double)ry);
        atomicAdd(&acc[S8(bb * 9 + grp * 3 + 2)], (double)rz);
    }
}

// ---------------- K6: finalize ------------------------------------------------------
__global__ void k_fin(const double* __restrict__ acc, float* __restrict__ out) {
    if (threadIdx.x < B * 9)
        out[threadIdx.x] = (float)(acc[S8(threadIdx.x)] * (1.0 / (double)N));
}

extern "C" void kernel_launch(void* const* d_in, const int* in_sizes, int n_in,
                              void* d_out, int out_size, void* d_ws, size_t ws_size,
                              hipStream_t stream) {
    const float* pc = (const float*)d_in[0];
    const float* Wf0 = (const float*)d_in[1];
    const float* Wd0 = (const float*)d_in[2];
    const float* g0 = (const float*)d_in[3];
    const float* b0 = (const float*)d_in[4];
    const float* Wf1 = (const float*)d_in[5];
    const float* Wd1 = (const float*)d_in[6];
    const float* g1 = (const float*)d_in[7];
    const float* b1 = (const float*)d_in[8];
    const float* gbn1 = (const float*)d_in[9];
    const float* bbn1 = (const float*)d_in[10];
    const float* Wf2 = (const float*)d_in[11];
    const float* Wd2 = (const float*)d_in[12];
    const float* g2 = (const float*)d_in[13];
    const float* b2 = (const float*)d_in[14];
    float* out = (float*)d_out;

    // Per-batch padded f64 stat slots (value-slot index -> byte offset via S8):
    //   st0: B*42 = 672 slots; st1: 672; stB: 672; st2: B*6 = 96; acc: 144.
    char* ws = (char*)d_ws;
    double* gws = (double*)ws;
    double* st0 = gws;                // slots [0, 672)
    double* st1 = gws + S8(672);      // [672, 1344)
    double* stB = gws + S8(1344);     // [1344, 2016)
    double* st2 = gws + S8(2016);     // [2016, 2112)
    double* acc = gws + S8(2112);     // [2112, 2256)  -> 2256*64 = 144384 B
    int* nbrbest = (int*)(ws + 262144);            // 256 KB
    float* xbuf = (float*)(ws + 524288);           // 63*NPTS f32 = 16.5 MB

    hipMemsetAsync(d_ws, 0, 144384, stream);  // zero all stat/acc slots

    k_knn<<<NBK, 256, 0, stream>>>(pc, Wf0, nbrbest, st0);
    k_l0st1<<<NBT, 256, 0, stream>>>(pc, nbrbest, Wf0, Wd0, g0, b0, Wf1, st0,
                                     xbuf, st1);
    k_l1stB<<<NBT, 256, 0, stream>>>(xbuf, Wf1, Wd1, g1, b1, st1, stB);
    k_bn1st2<<<NBT, 256, 0, stream>>>(xbuf, gbn1, bbn1, Wf2, stB, st2);
    k_acc<<<NBT, 256, 0, stream>>>(xbuf, gbn1, bbn1, Wf2, Wd2, g2, b2, stB, st2, acc);
    k_fin<<<1, 256, 0, stream>>>(acc, out);
}